// Round 8
// baseline (848.369 us; speedup 1.0000x reference)
//
#include <hip/hip_runtime.h>
#include <hip/hip_fp16.h>

#define N_NODES 100000
#define N_EDGES 1600000
#define N_GRAPHS 512
#define F 128
#define N_CONVS 4
#define SCAN_NBLK ((N_NODES + 1023) / 1024)   // 98

// two-phase fill, 256 subwindows so phase-B scatter fits in LDS
#define SUBW 256
#define SUBW_NODES 391                         // ceil(100000/256)
#define SCAP 7040                              // per-subwindow staging cap (mean 6256 + 10 sigma)
#define ACHUNK 4096
#define BINA_BLOCKS ((N_EDGES + ACHUNK - 1) / ACHUNK)  // 391
#define EBUF 8192                              // LDS edge buffer (mean 6256 + 24 sigma)

// channel-blocked aggregation: 8 blocks of 16 channels; XCD k owns block k
#define AGG_NODES_PER_BLK 8
#define AGG_CHUNKS ((N_NODES + AGG_NODES_PER_BLK - 1) / AGG_NODES_PER_BLK)  // 12500

// packed W2 row stride: 256 bf16 (hi/lo interleaved) padded to 264 = 132 dwords
#define W2_STRIDE 132
#define W2_LAYER (128 * W2_STRIDE)            // dwords per layer

typedef __attribute__((ext_vector_type(8))) short short8;   // 8 bf16 (4 VGPRs)
typedef __attribute__((ext_vector_type(4))) float f32x4;

union FragU { uint4 u; short8 v; };
union HU4 { uint4 u; __half2 h[4]; };

// split f into truncated-bf16 hi/lo, packed (hi in low16, lo in high16).
__device__ __forceinline__ unsigned int pack_hilo(float f) {
    unsigned int u = __float_as_uint(f);
    unsigned int hb = u & 0xFFFF0000u;
    float d = f - __uint_as_float(hb);
    unsigned int lb = __float_as_uint(d) >> 16;
    return (u >> 16) | (lb << 16);
}

// ---------------- CSR build ----------------

__global__ void dinv_kernel(const int* __restrict__ cnt, float* __restrict__ dinv) {
    int n = blockIdx.x * blockDim.x + threadIdx.x;
    if (n < N_NODES) dinv[n] = rsqrtf((float)cnt[n] + 2.0f);  // improved=True
}

__global__ void scan1_kernel(const int* __restrict__ cnt, int* __restrict__ excl,
                             int* __restrict__ blksum) {
    __shared__ int sums[256];
    int t = threadIdx.x;
    int base = blockIdx.x * 1024 + t * 4;
    int v0 = 0, v1 = 0, v2 = 0, v3 = 0;
    if (base + 0 < N_NODES) v0 = cnt[base + 0];
    if (base + 1 < N_NODES) v1 = cnt[base + 1];
    if (base + 2 < N_NODES) v2 = cnt[base + 2];
    if (base + 3 < N_NODES) v3 = cnt[base + 3];
    int s = v0 + v1 + v2 + v3;
    sums[t] = s;
    __syncthreads();
    for (int off = 1; off < 256; off <<= 1) {
        int y = (t >= off) ? sums[t - off] : 0;
        __syncthreads();
        sums[t] += y;
        __syncthreads();
    }
    int pre = sums[t] - s;
    if (base + 0 < N_NODES) excl[base + 0] = pre;
    if (base + 1 < N_NODES) excl[base + 1] = pre + v0;
    if (base + 2 < N_NODES) excl[base + 2] = pre + v0 + v1;
    if (base + 3 < N_NODES) excl[base + 3] = pre + v0 + v1 + v2;
    if (t == 255) blksum[blockIdx.x] = sums[255];
}

__global__ void scan2_kernel(int* __restrict__ blksum, int nblk) {
    __shared__ int sh[128];
    int t = threadIdx.x;
    int v = (t < nblk) ? blksum[t] : 0;
    sh[t] = v;
    __syncthreads();
    for (int off = 1; off < 128; off <<= 1) {
        int y = (t >= off) ? sh[t - off] : 0;
        __syncthreads();
        sh[t] += y;
        __syncthreads();
    }
    if (t < nblk) blksum[t] = sh[t] - v;
}

__global__ void scan3_kernel(int* __restrict__ rowptr, const int* __restrict__ blksum) {
    int t = threadIdx.x;
    int base = blockIdx.x * 1024 + t * 4;
    int off = blksum[blockIdx.x];
#pragma unroll
    for (int i = 0; i < 4; i++) {
        int idx = base + i;
        if (idx < N_NODES) rowptr[idx] += off;
    }
    if (blockIdx.x == 0 && t == 0) rowptr[N_NODES] = N_EDGES;
}

// ---------------- Two-phase CSR fill, LDS-ordered ----------------
// Measured lessons:
//  (1) gfx950 L2 does NOT merge temporally-scattered 8 B stores — every
//      global-scatter scheme paid ~6x write-back amplification. Scatter in
//      LDS, write out coalesced.
//  (2) gfx950 global atomics scattered over a small array are also ~64 B
//      write-back each. Count in LDS per subwindow instead (subcount).

__global__ __launch_bounds__(256) void binA_kernel(
        const int* __restrict__ src, const int* __restrict__ dst,
        int* __restrict__ cursor, int2* __restrict__ staging) {
    __shared__ int2 buf[ACHUNK];                 // 32 KB
    __shared__ int cnt_s[SUBW], off_s[SUBW], cur_s[SUBW], gb_s[SUBW], sh[SUBW];
    int t = threadIdx.x;
    cnt_s[t] = 0;
    __syncthreads();

    int base = blockIdx.x * ACHUNK;
    int n = N_EDGES - base;
    if (n > ACHUNK) n = ACHUNK;

    // pass 1: count bins
    for (int li = t; li < n; li += 256)
        atomicAdd(&cnt_s[dst[base + li] / SUBW_NODES], 1);
    __syncthreads();

    // exclusive scan over 256 bins
    int v = cnt_s[t];
    sh[t] = v;
    __syncthreads();
    for (int off = 1; off < SUBW; off <<= 1) {
        int y = (t >= off) ? sh[t - off] : 0;
        __syncthreads();
        sh[t] += y;
        __syncthreads();
    }
    int excl = sh[t] - v;
    off_s[t] = excl;
    cur_s[t] = excl;
    gb_s[t] = atomicAdd(&cursor[t], v);
    __syncthreads();

    // pass 2: re-read (L2-hot) and scatter into LDS bin-contiguous buffer
    for (int li = t; li < n; li += 256) {
        int e = base + li;
        int d = dst[e], s = src[e];
        int p = atomicAdd(&cur_s[d / SUBW_NODES], 1);
        buf[p] = make_int2(s, d);
    }
    __syncthreads();

    // flush: contiguous ~128 B runs per bin into per-subwindow staging
    for (int i = t; i < n; i += 256) {
        int2 e = buf[i];
        int w = e.y / SUBW_NODES;
        int idx = gb_s[w] + (i - off_s[w]);
        if (idx < SCAP) staging[(size_t)w * SCAP + idx] = e;
    }
}

__global__ __launch_bounds__(256) void subcount_kernel(
        const int2* __restrict__ staging, const int* __restrict__ cursor,
        int* __restrict__ cnt) {
    __shared__ int hist[SUBW_NODES];
    int b = blockIdx.x, t = threadIdx.x;
    int n0 = b * SUBW_NODES;
    int n1 = n0 + SUBW_NODES;
    if (n1 > N_NODES) n1 = N_NODES;
    int nn = n1 - n0;
    for (int i = t; i < nn; i += 256) hist[i] = 0;
    __syncthreads();
    int m = cursor[b];
    if (m > SCAP) m = SCAP;
    for (int i = t; i < m; i += 256) {
        int d = staging[(size_t)b * SCAP + i].y;
        atomicAdd(&hist[d - n0], 1);
    }
    __syncthreads();
    for (int i = t; i < nn; i += 256) cnt[n0 + i] = hist[i];
}

__global__ __launch_bounds__(512) void binB_kernel(
        const int2* __restrict__ staging, const int* __restrict__ cursor,
        const int* __restrict__ rowptr, const float* __restrict__ dinv,
        int2* __restrict__ edges) {
    __shared__ int rowl[SUBW_NODES + 1];
    __shared__ int lcur[SUBW_NODES];
    __shared__ int2 ebuf[EBUF];                  // 64 KB
    int b = blockIdx.x, t = threadIdx.x;
    int n0 = b * SUBW_NODES;
    int n1 = n0 + SUBW_NODES;
    if (n1 > N_NODES) n1 = N_NODES;
    int nn = n1 - n0;

    for (int i = t; i <= nn; i += 512) rowl[i] = rowptr[n0 + i];
    for (int i = t; i < nn; i += 512) lcur[i] = 0;
    __syncthreads();

    int gb = rowl[0];
    int total = rowl[nn] - gb;
    int m = cursor[b];
    if (m > SCAP) m = SCAP;

    for (int i = t; i < m; i += 512) {
        int2 e = staging[(size_t)b * SCAP + i];
        int s = e.x, d = e.y;
        float wt = dinv[s] * dinv[d];
        int dl = d - n0;
        int lpos = (rowl[dl] - gb) + atomicAdd(&lcur[dl], 1);
        if (lpos < EBUF) ebuf[lpos] = make_int2(s, __float_as_int(wt));
    }
    __syncthreads();

    // fully coalesced ordered write-out of this subwindow's CSR range
    for (int i = t; i < total; i += 512)
        if (i < EBUF) edges[gb + i] = ebuf[i];
}

// ---------------- W pre-pack: conv_w[L][k][n] -> W2g[L][n][132 dwords] ----------------

__global__ void wpack_kernel(const float* __restrict__ conv_w, unsigned int* __restrict__ W2g) {
    int idx = blockIdx.x * 256 + threadIdx.x;
    if (idx < N_CONVS * 16384) {
        int L = idx >> 14;
        int e = idx & 16383;
        int k = e >> 7;
        int n = e & 127;
        float f = conv_w[(size_t)L * 16384 + k * 128 + n];
        W2g[(size_t)L * W2_LAYER + n * W2_STRIDE + k] = pack_hilo(f);
    }
}

// ---------------- MFMA GEMM: H = X @ W via split-bf16, 32 rows/wave ------
// Output (and fp16 input) use the CHANNEL-BLOCKED layout
//   buf[(cb*N_NODES + node)*16 + (c&15)],  cb = c>>4
// so each XCD's aggregation gather touches only its own 3.2 MB channel block.

template<bool F16IN>
__global__ __launch_bounds__(256, 2) void gemm_mfma_t(const void* __restrict__ Xv,
                                                      const unsigned int* __restrict__ W2g,
                                                      __half* __restrict__ Hh) {
    __shared__ unsigned int wlds[128 * W2_STRIDE];   // 67584 B
    int t = threadIdx.x;

    {   // stage packed W (16896 dwords)
        const uint4* s4 = (const uint4*)W2g;
        uint4* d4 = (uint4*)wlds;
#pragma unroll
        for (int i = 0; i < 17; i++) {
            int idx = i * 256 + t;
            if (idx < (128 * W2_STRIDE) / 4) d4[idx] = s4[idx];
        }
    }
    __syncthreads();

    int w = t >> 6;
    int l = t & 63;
    int m = l & 15;        // A row within tile / B col / C col
    int q = l >> 4;        // quad: k-offset q*8, C row-offset q*4
    int r0 = blockIdx.x * 128 + w * 32 + m;
    int r1 = r0 + 16;
    int r0c = (r0 > N_NODES - 1) ? (N_NODES - 1) : r0;
    int r1c = (r1 > N_NODES - 1) ? (N_NODES - 1) : r1;

    uint4 a0[8], a1[8];
#pragma unroll
    for (int i = 0; i < 8; i++) {
        if constexpr (F16IN) {
            // blocked layout: channels 16i+4q..+3 = block i, local ch 4q..4q+3
            const uint2* X2 = (const uint2*)Xv;   // 4 halves per uint2
            uint2 hv = X2[((size_t)i * N_NODES + r0c) * 4 + q];
            float2 f0 = __half22float2(*(const __half2*)&hv.x);
            float2 f1 = __half22float2(*(const __half2*)&hv.y);
            a0[i].x = pack_hilo(f0.x); a0[i].y = pack_hilo(f0.y);
            a0[i].z = pack_hilo(f1.x); a0[i].w = pack_hilo(f1.y);
            uint2 gv = X2[((size_t)i * N_NODES + r1c) * 4 + q];
            float2 g0 = __half22float2(*(const __half2*)&gv.x);
            float2 g1 = __half22float2(*(const __half2*)&gv.y);
            a1[i].x = pack_hilo(g0.x); a1[i].y = pack_hilo(g0.y);
            a1[i].z = pack_hilo(g1.x); a1[i].w = pack_hilo(g1.y);
        } else {
            const float4* X4 = (const float4*)Xv;  // fp32 row-major input (layer 0)
            float4 xv = X4[(size_t)r0c * 32 + i * 4 + q];
            a0[i].x = pack_hilo(xv.x); a0[i].y = pack_hilo(xv.y);
            a0[i].z = pack_hilo(xv.z); a0[i].w = pack_hilo(xv.w);
            float4 yv = X4[(size_t)r1c * 32 + i * 4 + q];
            a1[i].x = pack_hilo(yv.x); a1[i].y = pack_hilo(yv.y);
            a1[i].z = pack_hilo(yv.z); a1[i].w = pack_hilo(yv.w);
        }
    }

    f32x4 acc0[8], acc1[8];
#pragma unroll
    for (int nb = 0; nb < 8; nb++) {
        acc0[nb] = (f32x4){0.f, 0.f, 0.f, 0.f};
        acc1[nb] = (f32x4){0.f, 0.f, 0.f, 0.f};
    }

#pragma unroll
    for (int nb = 0; nb < 8; nb++) {
        const unsigned int* wb = &wlds[(nb * 16 + m) * W2_STRIDE];
#pragma unroll
        for (int i = 0; i < 8; i++) {
            uint4 b = *(const uint4*)(wb + i * 16 + q * 4);
            FragU fa0, fa1, fb, fr;
            fa0.u = a0[i]; fa1.u = a1[i]; fb.u = b;
            acc0[nb] = __builtin_amdgcn_mfma_f32_16x16x32_bf16(fa0.v, fb.v, acc0[nb], 0, 0, 0);
            acc1[nb] = __builtin_amdgcn_mfma_f32_16x16x32_bf16(fa1.v, fb.v, acc1[nb], 0, 0, 0);
            fr.u.x = (b.x >> 16) | (b.x << 16);
            fr.u.y = (b.y >> 16) | (b.y << 16);
            fr.u.z = (b.z >> 16) | (b.z << 16);
            fr.u.w = (b.w >> 16) | (b.w << 16);
            acc0[nb] = __builtin_amdgcn_mfma_f32_16x16x32_bf16(fa0.v, fr.v, acc0[nb], 0, 0, 0);
            acc1[nb] = __builtin_amdgcn_mfma_f32_16x16x32_bf16(fa1.v, fr.v, acc1[nb], 0, 0, 0);
        }
    }

    // C/D: col = m, row = q*4 + r; write channel-blocked: block nb, local ch m
    int rbase = blockIdx.x * 128 + w * 32 + q * 4;
#pragma unroll
    for (int nb = 0; nb < 8; nb++) {
#pragma unroll
        for (int r = 0; r < 4; r++) {
            int row = rbase + r;
            if (row < N_NODES)
                Hh[((size_t)nb * N_NODES + row) * 16 + m] = __float2half(acc0[nb][r]);
            int row1 = row + 16;
            if (row1 < N_NODES)
                Hh[((size_t)nb * N_NODES + row1) * 16 + m] = __float2half(acc1[nb][r]);
        }
    }
}

// ---------------- Channel-blocked aggregation ----------------
// x_out = relu(agg + 2*dinv^2*h + b), fp16 blocked in/out.
// cb = blockIdx&7 -> (round-robin block->XCD map) XCD k only gathers channel
// block k: a 3.2 MB hot set that FITS its private 4 MB L2. The old full-row
// gather missed to the LLC for ~all of H (193 MB FETCH, 3.6 TB/s ceiling).
// Cost: edges re-streamed once per cb (8 x 12.8 MB, sequential, LLC-served).
// Wave = 2 nodes x 16 edge-slots x 2 lanes (uint4 = 8ch each). No LDS.

__global__ __launch_bounds__(256) void aggb_kernel(const uint4* __restrict__ Hq,
                                                   const int* __restrict__ rowptr,
                                                   const int2* __restrict__ edges,
                                                   const float* __restrict__ dinv,
                                                   const float4* __restrict__ bias4,
                                                   uint4* __restrict__ Xo) {
    int cb = blockIdx.x & 7;
    int chunk = blockIdx.x >> 3;
    int lane = threadIdx.x & 63;
    int wv = threadIdx.x >> 6;
    int node = chunk * AGG_NODES_PER_BLK + wv * 2 + (lane >> 5);
    if (node >= N_NODES) return;
    int l5 = lane & 31;
    int slot = l5 >> 1;       // 16 edge slots per node
    int half = lane & 1;      // which uint4 (8 of the 16 channels)
    size_t cbase = (size_t)cb * N_NODES;

    int lo = rowptr[node];
    int hi = rowptr[node + 1];

    float4 a0 = make_float4(0.f, 0.f, 0.f, 0.f);
    float4 a1 = make_float4(0.f, 0.f, 0.f, 0.f);

    for (int i = lo + slot; i < hi; i += 16) {
        int2 e = edges[i];
        float w = __int_as_float(e.y);
        HU4 x; x.u = Hq[(cbase + e.x) * 2 + half];
        float2 p0 = __half22float2(x.h[0]);
        float2 p1 = __half22float2(x.h[1]);
        float2 p2 = __half22float2(x.h[2]);
        float2 p3 = __half22float2(x.h[3]);
        a0.x = fmaf(w, p0.x, a0.x); a0.y = fmaf(w, p0.y, a0.y);
        a0.z = fmaf(w, p1.x, a0.z); a0.w = fmaf(w, p1.y, a0.w);
        a1.x = fmaf(w, p2.x, a1.x); a1.y = fmaf(w, p2.y, a1.y);
        a1.z = fmaf(w, p3.x, a1.z); a1.w = fmaf(w, p3.y, a1.w);
    }

    // reduce 16 slots (lane deltas 16,8,4,2 keep half parity)
#pragma unroll
    for (int d = 16; d >= 2; d >>= 1) {
        a0.x += __shfl_down(a0.x, d, 64); a0.y += __shfl_down(a0.y, d, 64);
        a0.z += __shfl_down(a0.z, d, 64); a0.w += __shfl_down(a0.w, d, 64);
        a1.x += __shfl_down(a1.x, d, 64); a1.y += __shfl_down(a1.y, d, 64);
        a1.z += __shfl_down(a1.z, d, 64); a1.w += __shfl_down(a1.w, d, 64);
    }

    if (slot == 0) {   // l5 in {0,1}, half = l5
        float dn = dinv[node];
        float sw = 2.0f * dn * dn;
        HU4 x; x.u = Hq[(cbase + node) * 2 + half];
        float2 p0 = __half22float2(x.h[0]);
        float2 p1 = __half22float2(x.h[1]);
        float2 p2 = __half22float2(x.h[2]);
        float2 p3 = __half22float2(x.h[3]);
        float4 bL = bias4[cb * 4 + half * 2];
        float4 bH = bias4[cb * 4 + half * 2 + 1];
        float4 rL, rH;
        rL.x = fmaxf(fmaf(sw, p0.x, a0.x) + bL.x, 0.f);
        rL.y = fmaxf(fmaf(sw, p0.y, a0.y) + bL.y, 0.f);
        rL.z = fmaxf(fmaf(sw, p1.x, a0.z) + bL.z, 0.f);
        rL.w = fmaxf(fmaf(sw, p1.y, a0.w) + bL.w, 0.f);
        rH.x = fmaxf(fmaf(sw, p2.x, a1.x) + bH.x, 0.f);
        rH.y = fmaxf(fmaf(sw, p2.y, a1.y) + bH.y, 0.f);
        rH.z = fmaxf(fmaf(sw, p3.x, a1.z) + bH.z, 0.f);
        rH.w = fmaxf(fmaf(sw, p3.y, a1.w) + bH.w, 0.f);
        HU4 o;
        o.h[0] = __floats2half2_rn(rL.x, rL.y);
        o.h[1] = __floats2half2_rn(rL.z, rL.w);
        o.h[2] = __floats2half2_rn(rH.x, rH.y);
        o.h[3] = __floats2half2_rn(rH.z, rH.w);
        Xo[(cbase + node) * 2 + half] = o.u;
    }
}

// ---------------- Fused mean-pool + FC1(relu) + FC2 (fp16 blocked x) ----------------

__global__ __launch_bounds__(256) void pool_fc_kernel(const __half* __restrict__ x,
                                                      const int* __restrict__ batch,
                                                      const float* __restrict__ fc1w,
                                                      const float* __restrict__ fc1b,
                                                      const float* __restrict__ fc2w,
                                                      const float* __restrict__ fc2b,
                                                      float* __restrict__ out) {
    __shared__ float part[2][F];
    __shared__ float pooled[F];
    __shared__ int bnd[2];
    __shared__ float red[2];
    int g = blockIdx.x, t = threadIdx.x;
    int c = t & 127, hlf = t >> 7;

    if (t < 2) {
        int target = g + t;
        int lo = 0, hi = N_NODES;
        while (lo < hi) {
            int m = (lo + hi) >> 1;
            if (batch[m] < target) lo = m + 1;
            else hi = m;
        }
        bnd[t] = lo;
    }
    __syncthreads();
    int lo = bnd[0], hi = bnd[1];

    // channel-blocked: x[(cb*N + n)*16 + (c&15)]
    size_t cboff = ((size_t)(c >> 4) * N_NODES) * 16 + (c & 15);

    float s = 0.f;
    int n = lo + hlf;
    for (; n + 6 < hi; n += 8) {
        float v0 = __half2float(x[cboff + (size_t)n * 16]);
        float v1 = __half2float(x[cboff + (size_t)(n + 2) * 16]);
        float v2 = __half2float(x[cboff + (size_t)(n + 4) * 16]);
        float v3 = __half2float(x[cboff + (size_t)(n + 6) * 16]);
        s += (v0 + v1) + (v2 + v3);
    }
    for (; n < hi; n += 2) s += __half2float(x[cboff + (size_t)n * 16]);
    part[hlf][c] = s;
    __syncthreads();

    if (t < F) {
        float cntf = fmaxf((float)(hi - lo), 1.0f);
        pooled[c] = (part[0][c] + part[1][c]) / cntf;
    }
    __syncthreads();

    if (t < F) {
        float acc = fc1b[t];
#pragma unroll 4
        for (int k = 0; k < F; k++) acc = fmaf(pooled[k], fc1w[k * F + t], acc);
        acc = fmaxf(acc, 0.f);

        float p = acc * fc2w[t];
#pragma unroll
        for (int o = 32; o > 0; o >>= 1) p += __shfl_down(p, o, 64);
        if ((t & 63) == 0) red[t >> 6] = p;
    }
    __syncthreads();
    if (t == 0) out[g] = red[0] + red[1] + fc2b[0];
}

// ---------------- launch ----------------

extern "C" void kernel_launch(void* const* d_in, const int* in_sizes, int n_in,
                              void* d_out, int out_size, void* d_ws, size_t ws_size,
                              hipStream_t stream) {
    const float* x_in   = (const float*)d_in[0];
    const int*   eidx   = (const int*)d_in[1];
    const int*   batch  = (const int*)d_in[2];
    const float* conv_w = (const float*)d_in[4];
    const float* conv_b = (const float*)d_in[5];
    const float* fc1w   = (const float*)d_in[6];
    const float* fc1b   = (const float*)d_in[7];
    const float* fc2w   = (const float*)d_in[8];
    const float* fc2b   = (const float*)d_in[9];
    float* out = (float*)d_out;

    const int* src = eidx;
    const int* dst = eidx + N_EDGES;

    char* ws = (char*)d_ws;
    size_t off = 0;
    auto alloc = [&](size_t bytes) -> char* {
        char* p = ws + off;
        off += (bytes + 255) & ~(size_t)255;
        return p;
    };
    __half* bufA  = (__half*)alloc((size_t)N_NODES * F * 2);   // 25.6 MB fp16 blocked (agg out)
    __half* bufH  = (__half*)alloc((size_t)N_NODES * F * 2);   // 25.6 MB fp16 blocked (gemm out)
    float*  dinv  = (float*)alloc((size_t)N_NODES * 4);
    int*    cnt   = (int*)alloc((size_t)N_NODES * 4);
    int*    rowp  = (int*)alloc((size_t)(N_NODES + 1) * 4);
    int2*   edges = (int2*)alloc((size_t)N_EDGES * 8);         // 12.8 MB packed
    unsigned int* W2g = (unsigned int*)alloc((size_t)N_CONVS * W2_LAYER * 4);  // 264 KB
    int*    blks  = (int*)alloc(128 * 4);
    int*    cursor = (int*)alloc(SUBW * 4);
    int2*   staging = (int2*)alloc((size_t)SUBW * SCAP * 8);   // 14.4 MB
    (void)ws_size; (void)in_sizes; (void)n_in; (void)out_size;

    // --- bucket edges first (needs no counts), then LDS-histogram counting ---
    hipMemsetAsync(cursor, 0, SUBW * 4, stream);
    binA_kernel<<<BINA_BLOCKS, 256, 0, stream>>>(src, dst, cursor, staging);
    subcount_kernel<<<SUBW, 256, 0, stream>>>(staging, cursor, cnt);

    // --- CSR prep + W pre-pack ---
    dinv_kernel<<<(N_NODES + 255) / 256, 256, 0, stream>>>(cnt, dinv);
    scan1_kernel<<<SCAN_NBLK, 256, 0, stream>>>(cnt, rowp, blks);
    scan2_kernel<<<1, 128, 0, stream>>>(blks, SCAN_NBLK);
    scan3_kernel<<<SCAN_NBLK, 256, 0, stream>>>(rowp, blks);
    wpack_kernel<<<(N_CONVS * 16384 + 255) / 256, 256, 0, stream>>>(conv_w, W2g);

    // --- LDS-ordered coalesced CSR fill ---
    binB_kernel<<<SUBW, 512, 0, stream>>>(staging, cursor, rowp, dinv, edges);

    // --- 4 GCN layers: MFMA GEMM (blocked fp16 out) + channel-blocked agg ---
    for (int L = 0; L < N_CONVS; L++) {
        if (L == 0)
            gemm_mfma_t<false><<<(N_NODES + 127) / 128, 256, 0, stream>>>(
                (const void*)x_in, W2g, bufH);
        else
            gemm_mfma_t<true><<<(N_NODES + 127) / 128, 256, 0, stream>>>(
                (const void*)bufA, W2g + (size_t)L * W2_LAYER, bufH);
        aggb_kernel<<<AGG_CHUNKS * 8, 256, 0, stream>>>(
            (const uint4*)bufH, rowp, edges, dinv,
            (const float4*)(conv_b + (size_t)L * F), (uint4*)bufA);
    }

    // --- mean-pool + FC head ---
    pool_fc_kernel<<<N_GRAPHS, 256, 0, stream>>>(bufA, batch, fc1w, fc1b, fc2w, fc2b, out);
}